// Round 7
// baseline (780.670 us; speedup 1.0000x reference)
//
#include <hip/hip_runtime.h>

static constexpr int   kBatch   = 2097152;
static constexpr int   H        = 32;
static constexpr float kActScale = 1.0f / 12.0f;
static constexpr float kAct2     = 1.0f / 6.0f;   // 2*ACT_SCALE

// Device-global table:
// [0,1024)    spA0        (softplus(raw_A_0), row-major [i][j])
// [1024,2048) spA1
// [2048,3072) spA0T       (transposed copy for backward)
// [3072,4096) spA1T
// [4096,4128) spAout      (softplus(raw_A_out))
// [4128]      cref        (dW/dI1 at z0 = 0)
__device__ float g_tab[4136];

__device__ __forceinline__ float rcp_f(float x) { return __fdividef(1.0f, x); }

__device__ __forceinline__ float sp_only(float x) {
    float e = __expf(-fabsf(x));
    return fmaxf(x, 0.0f) + __logf(1.0f + e);
}
__device__ __forceinline__ float sig_only(float x) {
    float e = __expf(-fabsf(x));
    float r = rcp_f(1.0f + e);
    return (x >= 0.0f) ? r : e * r;
}
// softplus(x), and sigmoid(x) via out-param. Stable for |x| up to hundreds.
__device__ __forceinline__ float sp_sig(float x, float& sig) {
    float e  = __expf(-fabsf(x));
    float oe = 1.0f + e;
    float r  = rcp_f(oe);
    sig = (x >= 0.0f) ? r : e * r;
    return fmaxf(x, 0.0f) + __logf(oe);
}

// 32-term gather dot; fully inlined+unrolled, a[] is wave-uniform (s_load).
__device__ __forceinline__ float dot32(const float* __restrict__ a,
                                       const float v[32]) {
    float u = 0.0f;
    #pragma unroll
    for (int j = 0; j < 32; j++) u = fmaf(a[j], v[j], u);
    return u;
}

// ---------------- prep: softplus tables + reference-gradient constant --------
__global__ __launch_bounds__(256) void icnn_prep(
    const float* __restrict__ rawA0, const float* __restrict__ rawA1,
    const float* __restrict__ rawAout,
    const float* __restrict__ W1,  const float* __restrict__ b1,
    const float* __restrict__ Wc0, const float* __restrict__ bc0,
    const float* __restrict__ Wc1, const float* __restrict__ bc1,
    const float* __restrict__ wout)
{
    __shared__ float sA0[1024], sA1[1024], sAout[32];
    const int t = threadIdx.x;
    for (int k = t; k < 1024; k += 256) { float v = sp_only(rawA0[k]); sA0[k] = v; g_tab[k] = v; }
    for (int k = t; k < 1024; k += 256) { float v = sp_only(rawA1[k]); sA1[k] = v; g_tab[1024 + k] = v; }
    if (t < 32) { float v = sp_only(rawAout[t]); sAout[t] = v; g_tab[4096 + t] = v; }
    __syncthreads();
    for (int k = t; k < 1024; k += 256) g_tab[2048 + k] = sA0[(k & 31) * 32 + (k >> 5)];
    for (int k = t; k < 1024; k += 256) g_tab[3072 + k] = sA1[(k & 31) * 32 + (k >> 5)];

    // reference gradient dW/dI1 at z0 = (0,0), wave-0 lanes 0..31
    if (t < 32) {
        const int i = t;
        float sa, sc0v;
        float zi = sp_sig(b1[i], sa);
        float u = 0.0f;
        for (int j = 0; j < 32; j++) u = fmaf(sA0[i * 32 + j], __shfl(zi, j, 64), u);
        float su; float t0 = sp_sig(u, su);
        float d0 = kAct2 * t0 * su;
        float spc = sp_sig(bc0[i], sc0v);
        float zn = fmaf(kActScale * t0, t0, spc);
        float u1 = 0.0f;
        for (int j = 0; j < 32; j++) u1 = fmaf(sA1[i * 32 + j], __shfl(zn, j, 64), u1);
        float su1; float t1 = sp_sig(u1, su1);
        float d1 = sAout[i] * kAct2 * t1 * su1;
        float contrib = Wc1[2 * i] * sAout[i] * sig_only(bc1[i]);
        float g = 0.0f;
        for (int j = 0; j < 32; j++) g = fmaf(sA1[j * 32 + i], __shfl(d1, j, 64), g);
        contrib = fmaf(Wc0[2 * i], g * sc0v, contrib);
        float gu0 = g * d0;
        float ga = 0.0f;
        for (int j = 0; j < 32; j++) ga = fmaf(sA0[j * 32 + i], __shfl(gu0, j, 64), ga);
        ga *= sa;
        contrib = fmaf(W1[2 * i], ga, contrib);
        for (int off = 16; off >= 1; off >>= 1)
            contrib += __shfl_down(contrib, off, 32);
        if (i == 0) g_tab[4128] = wout[0] + contrib;
    }
}

// ---------------- main: thread-per-row, LDS-streamed intermediates -----------
// R6 post-mortem: unified VGPR/AGPR file -- compiler parks the ~100-float
// live state in AGPRs; every matvec operand read becomes v_accvgpr_read
// (~4096 extra VALU ops = the persistent 2.7x bloat). Fix: make peak live
// state STRUCTURALLY < 64 regs. Cross-phase vectors live in private
// per-thread LDS slots (no barriers): d0 -> slot A; zn/d1/gg time-share
// slot B (each is fully read into regs before its successor is written).
// Each gather phase: 32-float input vec in regs + 8 accumulators = ~52 live.
// LDS: 64 dwords/thread = 64 KB/block -> 2 blocks/CU -> 4 waves/SIMD.
__global__ __launch_bounds__(256) void icnn_main(
    const float* __restrict__ eps,
    const float* __restrict__ W1,  const float* __restrict__ b1,
    const float* __restrict__ Wc0, const float* __restrict__ bc0,
    const float* __restrict__ Wc1, const float* __restrict__ bc1,
    const float* __restrict__ wout,
    float* __restrict__ out)
{
    __shared__ float sm[64 * 256];            // 64 KB
    const int tid = threadIdx.x;
    const int row = blockIdx.x * 256 + tid;

    float* __restrict__ sd0 = sm + tid;              // d0_i at sd0[i*256]
    float* __restrict__ svv = sm + 32 * 256 + tid;   // zn/d1/gg at svv[k*256]

    const float e11 = eps[row * 3 + 0];
    const float e22 = eps[row * 3 + 1];
    const float e12 = eps[row * 3 + 2];
    const float x1 = e11 + e22;
    const float x2 = e11 * e11 + 2.0f * e12 * e12 + e22 * e22;

    const float* __restrict__ A0   = g_tab;
    const float* __restrict__ A1   = g_tab + 1024;
    const float* __restrict__ A0T  = g_tab + 2048;
    const float* __restrict__ A1T  = g_tab + 3072;
    const float* __restrict__ aout = g_tab + 4096;

    float g0 = wout[0], gq = wout[1];
    float v[32];                               // the active input vector

    // ---- P1: z = softplus(W1 z0 + b1)  [live: v(32)]
    #pragma unroll
    for (int i = 0; i < H; i++) {
        float a = fmaf(W1[2 * i], x1, fmaf(W1[2 * i + 1], x2, b1[i]));
        v[i] = sp_only(a);
    }

    // ---- P2: u = A0 z (blocks of 8); d0 -> LDS(A); zn -> LDS(B)
    #pragma unroll
    for (int b = 0; b < 4; b++) {
        float u[8];
        #pragma unroll
        for (int t = 0; t < 8; t++) u[t] = dot32(A0 + (b * 8 + t) * 32, v);
        #pragma unroll
        for (int t = 0; t < 8; t++) {
            const int i = b * 8 + t;
            float su; float tt = sp_sig(u[t], su);
            sd0[i * 256] = kAct2 * tt * su;
            float c = fmaf(Wc0[2 * i], x1, fmaf(Wc0[2 * i + 1], x2, bc0[i]));
            svv[i * 256] = fmaf(kActScale * tt, tt, sp_only(c));
        }
    }

    // ---- P3: v <- zn; u1 = A1 zn; d1 -> LDS(B); fold c1-skip
    #pragma unroll
    for (int k = 0; k < 32; k++) v[k] = svv[k * 256];
    #pragma unroll
    for (int b = 0; b < 4; b++) {
        float u[8];
        #pragma unroll
        for (int t = 0; t < 8; t++) u[t] = dot32(A1 + (b * 8 + t) * 32, v);
        #pragma unroll
        for (int t = 0; t < 8; t++) {
            const int i = b * 8 + t;
            float su; float tt = sp_sig(u[t], su);
            float c = fmaf(Wc1[2 * i], x1, fmaf(Wc1[2 * i + 1], x2, bc1[i]));
            float w = aout[i] * sig_only(c);
            g0 = fmaf(Wc1[2 * i], w, g0);
            gq = fmaf(Wc1[2 * i + 1], w, gq);
            svv[i * 256] = aout[i] * kAct2 * tt * su;
        }
    }

    // ---- P4: v <- d1; acc = A1^T d1; fold c0-skip (recompute sigmoid(c0),
    //          different association than P2); gg = acc*d0 -> LDS(B)
    #pragma unroll
    for (int k = 0; k < 32; k++) v[k] = svv[k * 256];
    #pragma unroll
    for (int b = 0; b < 4; b++) {
        float u[8];
        #pragma unroll
        for (int t = 0; t < 8; t++) u[t] = dot32(A1T + (b * 8 + t) * 32, v);
        #pragma unroll
        for (int t = 0; t < 8; t++) {
            const int i = b * 8 + t;
            float c = fmaf(Wc0[2 * i + 1], x2, fmaf(Wc0[2 * i], x1, bc0[i]));
            float w = u[t] * sig_only(c);
            g0 = fmaf(Wc0[2 * i], w, g0);
            gq = fmaf(Wc0[2 * i + 1], w, gq);
            svv[i * 256] = u[t] * sd0[i * 256];
        }
    }

    // ---- P5: v <- gg; acc = A0^T gg; recompute sigmoid(a) (different
    //          association than P1); final fold
    #pragma unroll
    for (int k = 0; k < 32; k++) v[k] = svv[k * 256];
    #pragma unroll
    for (int b = 0; b < 4; b++) {
        float u[8];
        #pragma unroll
        for (int t = 0; t < 8; t++) u[t] = dot32(A0T + (b * 8 + t) * 32, v);
        #pragma unroll
        for (int t = 0; t < 8; t++) {
            const int i = b * 8 + t;
            float a = fmaf(W1[2 * i + 1], x2, fmaf(W1[2 * i], x1, b1[i]));
            float ga = u[t] * sig_only(a);
            g0 = fmaf(W1[2 * i], ga, g0);
            gq = fmaf(W1[2 * i + 1], ga, gq);
        }
    }

    const float cref = g_tab[4128];
    const float dI1 = g0 - cref;
    const float dI2 = gq;
    out[row * 3 + 0] = fmaf(2.0f * e11, dI2, dI1);
    out[row * 3 + 1] = fmaf(2.0f * e22, dI2, dI1);
    out[row * 3 + 2] = 2.0f * e12 * dI2;
}

extern "C" void kernel_launch(void* const* d_in, const int* in_sizes, int n_in,
                              void* d_out, int out_size, void* d_ws, size_t ws_size,
                              hipStream_t stream)
{
    (void)in_sizes; (void)n_in; (void)out_size; (void)d_ws; (void)ws_size;
    const float* eps    = (const float*)d_in[0];
    const float* W1     = (const float*)d_in[1];
    const float* b1     = (const float*)d_in[2];
    const float* rawA0  = (const float*)d_in[3];
    const float* rawA1  = (const float*)d_in[4];
    const float* Wc0    = (const float*)d_in[5];
    const float* bc0    = (const float*)d_in[6];
    const float* Wc1    = (const float*)d_in[7];
    const float* bc1    = (const float*)d_in[8];
    const float* rawAout= (const float*)d_in[9];
    const float* wout   = (const float*)d_in[10];
    float* out = (float*)d_out;

    icnn_prep<<<1, 256, 0, stream>>>(rawA0, rawA1, rawAout, W1, b1, Wc0, bc0, Wc1, bc1, wout);
    icnn_main<<<kBatch / 256, 256, 0, stream>>>(eps, W1, b1, Wc0, bc0, Wc1, bc1, wout, out);
}

// Round 8
// 348.894 us; speedup vs baseline: 2.2376x; 2.2376x over previous
//
#include <hip/hip_runtime.h>

typedef __attribute__((ext_vector_type(8)))  short s8b;    // 8 x bf16
typedef __attribute__((ext_vector_type(16))) float f32x16; // mfma C/D

static constexpr int   kBatch    = 2097152;
static constexpr float kActScale = 1.0f / 12.0f;
static constexpr float kAct2     = 1.0f / 6.0f;   // 2*ACT_SCALE

// fp32 table: [4096,4128) aout ; [4128] cref
__device__ float  g_tab[4136];
// bf16 hi/lo weight tables, row-major 32x32 each:
// [0]=A0 hi [1]=A0 lo [2]=A1 hi [3]=A1 lo [4]=A1T hi [5]=A1T lo [6]=A0T hi [7]=A0T lo
__device__ __attribute__((aligned(16))) ushort g_bt[8][1024];

__device__ __forceinline__ float rcp_f(float x) { return __fdividef(1.0f, x); }
__device__ __forceinline__ float sp_only(float x) {
    float e = __expf(-fabsf(x));
    return fmaxf(x, 0.0f) + __logf(1.0f + e);
}
__device__ __forceinline__ float sig_only(float x) {
    float e = __expf(-fabsf(x));
    float r = rcp_f(1.0f + e);
    return (x >= 0.0f) ? r : e * r;
}
__device__ __forceinline__ float sp_sig(float x, float& sig) {
    float e  = __expf(-fabsf(x));
    float oe = 1.0f + e;
    float r  = rcp_f(oe);
    sig = (x >= 0.0f) ? r : e * r;
    return fmaxf(x, 0.0f) + __logf(oe);
}

__device__ __forceinline__ uint  bf16u(float x) {
    uint u = __float_as_uint(x);
    return (u + 0x7FFFu + ((u >> 16) & 1u)) >> 16;      // RNE
}
__device__ __forceinline__ float bf16f(uint h) { return __uint_as_float(h << 16); }
// pack {hi = bf16_rne(v)} in low16, {lo = top16 of (v - hi)} in high16
__device__ __forceinline__ uint packhl(float v) {
    uint hi = bf16u(v);
    float lo = v - bf16f(hi);
    return hi | (__float_as_uint(lo) & 0xFFFF0000u);
}

// ---------------- prep: bf16 hi/lo tables + aout + cref ----------------------
__global__ __launch_bounds__(256) void icnn_prep(
    const float* __restrict__ rawA0, const float* __restrict__ rawA1,
    const float* __restrict__ rawAout,
    const float* __restrict__ W1,  const float* __restrict__ b1,
    const float* __restrict__ Wc0, const float* __restrict__ bc0,
    const float* __restrict__ Wc1, const float* __restrict__ bc1,
    const float* __restrict__ wout)
{
    __shared__ float sA0[1024], sA1[1024], sAout[32];
    const int t = threadIdx.x;
    for (int k = t; k < 1024; k += 256) sA0[k] = sp_only(rawA0[k]);
    for (int k = t; k < 1024; k += 256) sA1[k] = sp_only(rawA1[k]);
    if (t < 32) { float v = sp_only(rawAout[t]); sAout[t] = v; g_tab[4096 + t] = v; }
    __syncthreads();
    for (int k = t; k < 1024; k += 256) {
        float v0 = sA0[k];
        uint h0 = bf16u(v0);
        g_bt[0][k] = (ushort)h0; g_bt[1][k] = (ushort)bf16u(v0 - bf16f(h0));
        float v1 = sA1[k];
        uint h1 = bf16u(v1);
        g_bt[2][k] = (ushort)h1; g_bt[3][k] = (ushort)bf16u(v1 - bf16f(h1));
        float v2 = sA1[(k & 31) * 32 + (k >> 5)];     // A1T[i][j] = A1[j][i]
        uint h2 = bf16u(v2);
        g_bt[4][k] = (ushort)h2; g_bt[5][k] = (ushort)bf16u(v2 - bf16f(h2));
        float v3 = sA0[(k & 31) * 32 + (k >> 5)];     // A0T
        uint h3 = bf16u(v3);
        g_bt[6][k] = (ushort)h3; g_bt[7][k] = (ushort)bf16u(v3 - bf16f(h3));
    }

    // cref: exact fp32 gradient dW/dI1 at z0 = 0 (wave-0 lanes 0..31)
    if (t < 32) {
        const int i = t;
        float sa, sc0v;
        float zi = sp_sig(b1[i], sa);
        float u = 0.0f;
        for (int j = 0; j < 32; j++) u = fmaf(sA0[i * 32 + j], __shfl(zi, j, 64), u);
        float su; float t0 = sp_sig(u, su);
        float d0 = kAct2 * t0 * su;
        float spc = sp_sig(bc0[i], sc0v);
        float zn = fmaf(kActScale * t0, t0, spc);
        float u1 = 0.0f;
        for (int j = 0; j < 32; j++) u1 = fmaf(sA1[i * 32 + j], __shfl(zn, j, 64), u1);
        float su1; float t1 = sp_sig(u1, su1);
        float d1 = sAout[i] * kAct2 * t1 * su1;
        float contrib = Wc1[2 * i] * sAout[i] * sig_only(bc1[i]);
        float g = 0.0f;
        for (int j = 0; j < 32; j++) g = fmaf(sA1[j * 32 + i], __shfl(d1, j, 64), g);
        contrib = fmaf(Wc0[2 * i], g * sc0v, contrib);
        float gu0 = g * d0;
        float ga = 0.0f;
        for (int j = 0; j < 32; j++) ga = fmaf(sA0[j * 32 + i], __shfl(gu0, j, 64), ga);
        ga *= sa;
        contrib = fmaf(W1[2 * i], ga, contrib);
        for (int off = 16; off >= 1; off >>= 1)
            contrib += __shfl_down(contrib, off, 32);
        if (i == 0) g_tab[4128] = wout[0] + contrib;
    }
}

// read one A-frag pair (hi,lo) from the junction buffer: tile T, k-half KH
#define RD1(FH, FL, T, KH) { \
    const uint* p = sw + (col + 32 * (T)) * 33 + 8 * half + 16 * (KH); \
    uint q0 = p[0], q1 = p[1], q2 = p[2], q3 = p[3]; \
    uint q4 = p[4], q5 = p[5], q6 = p[6], q7 = p[7]; \
    union { s8b v; uint d[4]; } uh, ul; \
    uh.d[0] = (q0 & 0xFFFFu) | (q1 << 16); ul.d[0] = (q0 >> 16) | (q1 & 0xFFFF0000u); \
    uh.d[1] = (q2 & 0xFFFFu) | (q3 << 16); ul.d[1] = (q2 >> 16) | (q3 & 0xFFFF0000u); \
    uh.d[2] = (q4 & 0xFFFFu) | (q5 << 16); ul.d[2] = (q4 >> 16) | (q5 & 0xFFFF0000u); \
    uh.d[3] = (q6 & 0xFFFFu) | (q7 << 16); ul.d[3] = (q6 >> 16) | (q7 & 0xFFFF0000u); \
    FH = uh.v; FL = ul.v; }

#define RDALL(P) \
    s8b P##h00, P##h01, P##h10, P##h11, P##l00, P##l01, P##l10, P##l11; \
    RD1(P##h00, P##l00, 0, 0) RD1(P##h01, P##l01, 0, 1) \
    RD1(P##h10, P##l10, 1, 0) RD1(P##h11, P##l11, 1, 1)

// D = (Ahi+Alo)(Bhi+Blo) dropping lo*lo; 6 mfma per tile
#define MATVEC(M, P, ACCA, ACCB) { \
    const s8b* Bh = (const s8b*)&g_bt[2 * (M)][0]; \
    const s8b* Bl = (const s8b*)&g_bt[2 * (M) + 1][0]; \
    const int i0 = col * 4 + half, i1 = i0 + 2; \
    s8b bh0 = Bh[i0], bh1 = Bh[i1], bl0 = Bl[i0], bl1 = Bl[i1]; \
    ACCA = __builtin_amdgcn_mfma_f32_32x32x16_bf16(P##h00, bh0, ACCA, 0, 0, 0); \
    ACCA = __builtin_amdgcn_mfma_f32_32x32x16_bf16(P##h01, bh1, ACCA, 0, 0, 0); \
    ACCA = __builtin_amdgcn_mfma_f32_32x32x16_bf16(P##l00, bh0, ACCA, 0, 0, 0); \
    ACCA = __builtin_amdgcn_mfma_f32_32x32x16_bf16(P##l01, bh1, ACCA, 0, 0, 0); \
    ACCA = __builtin_amdgcn_mfma_f32_32x32x16_bf16(P##h00, bl0, ACCA, 0, 0, 0); \
    ACCA = __builtin_amdgcn_mfma_f32_32x32x16_bf16(P##h01, bl1, ACCA, 0, 0, 0); \
    ACCB = __builtin_amdgcn_mfma_f32_32x32x16_bf16(P##h10, bh0, ACCB, 0, 0, 0); \
    ACCB = __builtin_amdgcn_mfma_f32_32x32x16_bf16(P##h11, bh1, ACCB, 0, 0, 0); \
    ACCB = __builtin_amdgcn_mfma_f32_32x32x16_bf16(P##l10, bh0, ACCB, 0, 0, 0); \
    ACCB = __builtin_amdgcn_mfma_f32_32x32x16_bf16(P##l11, bh1, ACCB, 0, 0, 0); \
    ACCB = __builtin_amdgcn_mfma_f32_32x32x16_bf16(P##h10, bl0, ACCB, 0, 0, 0); \
    ACCB = __builtin_amdgcn_mfma_f32_32x32x16_bf16(P##h11, bl1, ACCB, 0, 0, 0); }

// ---------------- main: one wave = 64 rows, MFMA matvecs ---------------------
// C-frag (row,col) mapping: col = lane&31, row = 4*(lane>>5) + (j&3) + 8*(j>>2)
// Junction buffer: wave-private [64 rows][33 dwords] (stride 33 -> conflict-
// free), each dword = {bf16 hi | low bits} of one activation. No barriers.
__global__ __launch_bounds__(256) __attribute__((amdgpu_waves_per_eu(3, 4)))
void icnn_main(
    const float* __restrict__ eps,
    const float* __restrict__ W1,  const float* __restrict__ b1,
    const float* __restrict__ Wc0, const float* __restrict__ bc0,
    const float* __restrict__ Wc1, const float* __restrict__ bc1,
    const float* __restrict__ wout,
    float* __restrict__ out)
{
    __shared__ uint sbuf[4 * 64 * 33];            // 33792 B
    const int tid  = threadIdx.x;
    const int lane = tid & 63, wib = tid >> 6;
    uint* __restrict__ sw = sbuf + wib * (64 * 33);
    const int col = lane & 31, half = lane >> 5;
    const long rowg = (long)(blockIdx.x * 4 + wib) * 64 + lane;

    const float e11 = eps[rowg * 3 + 0];
    const float e22 = eps[rowg * 3 + 1];
    const float e12 = eps[rowg * 3 + 2];
    const float x1 = e11 + e22;
    const float x2 = e11 * e11 + 2.0f * e12 * e12 + e22 * e22;

    float g0 = wout[0], gq = wout[1];

    // ---- Stage A: z = sp(W1 z0 + b1) exactly, per-row; junction-write hi/lo
    #pragma unroll
    for (int u = 0; u < 32; u++) {
        float a = fmaf(W1[2 * u], x1, fmaf(W1[2 * u + 1], x2, b1[u]));
        sw[lane * 33 + u] = packhl(sp_only(a));
    }

    // ---- Stage B: u0 = Z A0^T (MFMA); d0 kept in frags; zn -> junction
    RDALL(z)
    f32x16 acc0a = {}, acc0b = {};
    MATVEC(0, z, acc0a, acc0b)

    // c0 pre-activation via tiny MFMA (bf16 x -> sp(c0) err ~1e-3, negligible)
    const float x1s = __shfl(x1, col),      x2s = __shfl(x2, col);
    const float x1o = __shfl(x1, 32 + col), x2o = __shfl(x2, 32 + col);
    union { s8b v; uint d[4]; } xa0, xa1, wb;
    xa0.d[1] = xa0.d[2] = xa0.d[3] = 0;
    xa1.d[1] = xa1.d[2] = xa1.d[3] = 0;
    wb.d[1] = wb.d[2] = wb.d[3] = 0;
    xa0.d[0] = half ? 0u : (bf16u(x1s) | (bf16u(x2s) << 16));
    xa1.d[0] = half ? 0u : (bf16u(x1o) | (bf16u(x2o) << 16));
    wb.d[0]  = half ? 0u : (bf16u(Wc0[2 * col]) | (bf16u(Wc0[2 * col + 1]) << 16));
    f32x16 zz = {};
    f32x16 c0pa = __builtin_amdgcn_mfma_f32_32x32x16_bf16(xa0.v, wb.v, zz, 0, 0, 0);
    f32x16 c0pb = __builtin_amdgcn_mfma_f32_32x32x16_bf16(xa1.v, wb.v, zz, 0, 0, 0);

    const float bc0c = bc0[col];
    f32x16 d0a, d0b;
    #pragma unroll
    for (int j = 0; j < 16; j++) {
        const int rowl = 4 * half + (j & 3) + 8 * (j >> 2);
        float su; float t = sp_sig(acc0a[j], su);
        d0a[j] = kAct2 * t * su;
        sw[rowl * 33 + col] = packhl(fmaf(kActScale * t, t, sp_only(c0pa[j] + bc0c)));
        float su2; float t2 = sp_sig(acc0b[j], su2);
        d0b[j] = kAct2 * t2 * su2;
        sw[(rowl + 32) * 33 + col] = packhl(fmaf(kActScale * t2, t2, sp_only(c0pb[j] + bc0c)));
    }

    // ---- Stage C: u1 = ZN A1^T; d1 -> junction; T1 fold (exact, per-row)
    RDALL(n)
    f32x16 acc1a = {}, acc1b = {};
    MATVEC(1, n, acc1a, acc1b)

    #pragma unroll
    for (int c = 0; c < 32; c++) {
        float c1 = fmaf(Wc1[2 * c], x1, fmaf(Wc1[2 * c + 1], x2, bc1[c]));
        float w = g_tab[4096 + c] * sig_only(c1);
        g0 = fmaf(Wc1[2 * c], w, g0);
        gq = fmaf(Wc1[2 * c + 1], w, gq);
    }

    const float aoutc = g_tab[4096 + col];
    #pragma unroll
    for (int j = 0; j < 16; j++) {
        const int rowl = 4 * half + (j & 3) + 8 * (j >> 2);
        float su; float t = sp_sig(acc1a[j], su);
        sw[rowl * 33 + col] = packhl(aoutc * kAct2 * t * su);
        float su2; float t2 = sp_sig(acc1b[j], su2);
        sw[(rowl + 32) * 33 + col] = packhl(aoutc * kAct2 * t2 * su2);
    }

    // ---- Stage D: g = D1 A1 (via A1T table); gg = g*d0 -> junction;
    //      T2 fold: transpose raw g, exact sig(c0) per-row
    RDALL(d)
    f32x16 acc2a = {}, acc2b = {};
    MATVEC(2, d, acc2a, acc2b)

    #pragma unroll
    for (int j = 0; j < 16; j++) {
        const int rowl = 4 * half + (j & 3) + 8 * (j >> 2);
        sw[rowl * 33 + col]        = packhl(acc2a[j] * d0a[j]);
        sw[(rowl + 32) * 33 + col] = packhl(acc2b[j] * d0b[j]);
    }
    RDALL(g)                        // gg frags (read before T2 overwrites)
    #pragma unroll
    for (int j = 0; j < 16; j++) {
        const int rowl = 4 * half + (j & 3) + 8 * (j >> 2);
        sw[rowl * 33 + col]        = __float_as_uint(acc2a[j]);
        sw[(rowl + 32) * 33 + col] = __float_as_uint(acc2b[j]);
    }
    #pragma unroll
    for (int c = 0; c < 32; c++) {
        float v  = __uint_as_float(sw[lane * 33 + c]);
        float c0 = fmaf(Wc0[2 * c], x1, fmaf(Wc0[2 * c + 1], x2, bc0[c]));
        float t2v = v * sig_only(c0);
        g0 = fmaf(Wc0[2 * c], t2v, g0);
        gq = fmaf(Wc0[2 * c + 1], t2v, gq);
    }

    // ---- Stage E: acc3 = GG A0 (via A0T table); T3 fold with exact sig(a)
    f32x16 acc3a = {}, acc3b = {};
    MATVEC(3, g, acc3a, acc3b)

    #pragma unroll
    for (int j = 0; j < 16; j++) {
        const int rowl = 4 * half + (j & 3) + 8 * (j >> 2);
        sw[rowl * 33 + col]        = __float_as_uint(acc3a[j]);
        sw[(rowl + 32) * 33 + col] = __float_as_uint(acc3b[j]);
    }
    #pragma unroll
    for (int c = 0; c < 32; c++) {
        float v = __uint_as_float(sw[lane * 33 + c]);
        float a = fmaf(W1[2 * c], x1, fmaf(W1[2 * c + 1], x2, b1[c]));
        float t3 = v * sig_only(a);
        g0 = fmaf(W1[2 * c], t3, g0);
        gq = fmaf(W1[2 * c + 1], t3, gq);
    }

    const float cref = g_tab[4128];
    const float dI1 = g0 - cref;
    const float dI2 = gq;
    out[rowg * 3 + 0] = fmaf(2.0f * e11, dI2, dI1);
    out[rowg * 3 + 1] = fmaf(2.0f * e22, dI2, dI1);
    out[rowg * 3 + 2] = 2.0f * e12 * dI2;
}

extern "C" void kernel_launch(void* const* d_in, const int* in_sizes, int n_in,
                              void* d_out, int out_size, void* d_ws, size_t ws_size,
                              hipStream_t stream)
{
    (void)in_sizes; (void)n_in; (void)out_size; (void)d_ws; (void)ws_size;
    const float* eps    = (const float*)d_in[0];
    const float* W1     = (const float*)d_in[1];
    const float* b1     = (const float*)d_in[2];
    const float* rawA0  = (const float*)d_in[3];
    const float* rawA1  = (const float*)d_in[4];
    const float* Wc0    = (const float*)d_in[5];
    const float* bc0    = (const float*)d_in[6];
    const float* Wc1    = (const float*)d_in[7];
    const float* bc1    = (const float*)d_in[8];
    const float* rawAout= (const float*)d_in[9];
    const float* wout   = (const float*)d_in[10];
    float* out = (float*)d_out;

    icnn_prep<<<1, 256, 0, stream>>>(rawA0, rawA1, rawAout, W1, b1, Wc0, bc0, Wc1, bc1, wout);
    icnn_main<<<kBatch / 256, 256, 0, stream>>>(eps, W1, b1, Wc0, bc0, Wc1, bc1, wout, out);
}

// Round 10
// 304.952 us; speedup vs baseline: 2.5600x; 1.1441x over previous
//
#include <hip/hip_runtime.h>

typedef __attribute__((ext_vector_type(8)))  short s8b;    // 8 x bf16
typedef __attribute__((ext_vector_type(16))) float f32x16; // mfma C/D

static constexpr int   kBatch    = 2097152;
static constexpr float kActScale = 1.0f / 12.0f;
static constexpr float kAct2     = 1.0f / 6.0f;   // 2*ACT_SCALE

// fp32 table: [4096,4128) aout ; [4128] cref
__device__ float  g_tab[4136];
// bf16 hi/lo weight tables, row-major 32x32 each:
// [0]=A0 hi [1]=A0 lo [2]=A1 hi [3]=A1 lo [4]=A1T hi [5]=A1T lo [6]=A0T hi [7]=A0T lo
__device__ __attribute__((aligned(16))) ushort g_bt[8][1024];

__device__ __forceinline__ float rcp_f(float x) { return __fdividef(1.0f, x); }
__device__ __forceinline__ float sp_only(float x) {
    float e = __expf(-fabsf(x));
    return fmaxf(x, 0.0f) + __logf(1.0f + e);
}
__device__ __forceinline__ float sig_only(float x) {
    float e = __expf(-fabsf(x));
    float r = rcp_f(1.0f + e);
    return (x >= 0.0f) ? r : e * r;
}
__device__ __forceinline__ float sp_sig(float x, float& sig) {
    float e  = __expf(-fabsf(x));
    float oe = 1.0f + e;
    float r  = rcp_f(oe);
    sig = (x >= 0.0f) ? r : e * r;
    return fmaxf(x, 0.0f) + __logf(oe);
}

__device__ __forceinline__ uint  bf16u(float x) {
    uint u = __float_as_uint(x);
    return (u + 0x7FFFu + ((u >> 16) & 1u)) >> 16;      // RNE
}
__device__ __forceinline__ float bf16f(uint h) { return __uint_as_float(h << 16); }

// ---------------- prep: bf16 hi/lo weight tables + aout + cref ---------------
__global__ __launch_bounds__(256) void icnn_prep(
    const float* __restrict__ rawA0, const float* __restrict__ rawA1,
    const float* __restrict__ rawAout,
    const float* __restrict__ W1,  const float* __restrict__ b1,
    const float* __restrict__ Wc0, const float* __restrict__ bc0,
    const float* __restrict__ Wc1, const float* __restrict__ bc1,
    const float* __restrict__ wout)
{
    __shared__ float sA0[1024], sA1[1024], sAout[32];
    const int t = threadIdx.x;
    for (int k = t; k < 1024; k += 256) sA0[k] = sp_only(rawA0[k]);
    for (int k = t; k < 1024; k += 256) sA1[k] = sp_only(rawA1[k]);
    if (t < 32) { float v = sp_only(rawAout[t]); sAout[t] = v; g_tab[4096 + t] = v; }
    __syncthreads();
    for (int k = t; k < 1024; k += 256) {
        float v0 = sA0[k];
        uint h0 = bf16u(v0);
        g_bt[0][k] = (ushort)h0; g_bt[1][k] = (ushort)bf16u(v0 - bf16f(h0));
        float v1 = sA1[k];
        uint h1 = bf16u(v1);
        g_bt[2][k] = (ushort)h1; g_bt[3][k] = (ushort)bf16u(v1 - bf16f(h1));
        float v2 = sA1[(k & 31) * 32 + (k >> 5)];     // A1T[i][j] = A1[j][i]
        uint h2 = bf16u(v2);
        g_bt[4][k] = (ushort)h2; g_bt[5][k] = (ushort)bf16u(v2 - bf16f(h2));
        float v3 = sA0[(k & 31) * 32 + (k >> 5)];     // A0T
        uint h3 = bf16u(v3);
        g_bt[6][k] = (ushort)h3; g_bt[7][k] = (ushort)bf16u(v3 - bf16f(h3));
    }

    // cref: exact fp32 gradient dW/dI1 at z0 = 0 (wave-0 lanes 0..31)
    if (t < 32) {
        const int i = t;
        float sa, sc0v;
        float zi = sp_sig(b1[i], sa);
        float u = 0.0f;
        for (int j = 0; j < 32; j++) u = fmaf(sA0[i * 32 + j], __shfl(zi, j, 64), u);
        float su; float t0 = sp_sig(u, su);
        float d0 = kAct2 * t0 * su;
        float spc = sp_sig(bc0[i], sc0v);
        float zn = fmaf(kActScale * t0, t0, spc);
        float u1 = 0.0f;
        for (int j = 0; j < 32; j++) u1 = fmaf(sA1[i * 32 + j], __shfl(zn, j, 64), u1);
        float su1; float t1 = sp_sig(u1, su1);
        float d1 = sAout[i] * kAct2 * t1 * su1;
        float contrib = Wc1[2 * i] * sAout[i] * sig_only(bc1[i]);
        float g = 0.0f;
        for (int j = 0; j < 32; j++) g = fmaf(sA1[j * 32 + i], __shfl(d1, j, 64), g);
        contrib = fmaf(Wc0[2 * i], g * sc0v, contrib);
        float gu0 = g * d0;
        float ga = 0.0f;
        for (int j = 0; j < 32; j++) ga = fmaf(sA0[j * 32 + i], __shfl(gu0, j, 64), ga);
        ga *= sa;
        contrib = fmaf(W1[2 * i], ga, contrib);
        for (int off = 16; off >= 1; off >>= 1)
            contrib += __shfl_down(contrib, off, 32);
        if (i == 0) g_tab[4128] = wout[0] + contrib;
    }
}

// A-frag read: __builtin_memcpy (char semantics -> aliases the ushort stores,
// so the compiler CANNOT hoist these loads above the junction writes; R9's
// NaN was exactly that TBAA reorder with a uint* cast).
// Junction: ushort[64][66] (132 B row stride -> bank = row%32, conflict-free).
#define RD1S(F, T, KH) { \
    const ushort* p = swh + (col + 32 * (T)) * 66 + 8 * half + 16 * (KH); \
    union { s8b v; uint d[4]; } u_; \
    __builtin_memcpy(&u_.d[0], p, 16); \
    F = u_.v; }

#define RDALLS(P) \
    s8b P##00, P##01, P##10, P##11; \
    RD1S(P##00, 0, 0) RD1S(P##01, 0, 1) RD1S(P##10, 1, 0) RD1S(P##11, 1, 1)

// D = Act_bf16 * (Whi + Wlo): 4 mfma per 32x32 tile, 8 per matvec
#define MATVEC(M, P, ACCA, ACCB) { \
    const s8b* Bh = (const s8b*)&g_bt[2 * (M)][0]; \
    const s8b* Bl = (const s8b*)&g_bt[2 * (M) + 1][0]; \
    const int i0 = col * 4 + half, i1 = i0 + 2; \
    s8b bh0 = Bh[i0], bh1 = Bh[i1], bl0 = Bl[i0], bl1 = Bl[i1]; \
    ACCA = __builtin_amdgcn_mfma_f32_32x32x16_bf16(P##00, bh0, ACCA, 0, 0, 0); \
    ACCA = __builtin_amdgcn_mfma_f32_32x32x16_bf16(P##01, bh1, ACCA, 0, 0, 0); \
    ACCA = __builtin_amdgcn_mfma_f32_32x32x16_bf16(P##00, bl0, ACCA, 0, 0, 0); \
    ACCA = __builtin_amdgcn_mfma_f32_32x32x16_bf16(P##01, bl1, ACCA, 0, 0, 0); \
    ACCB = __builtin_amdgcn_mfma_f32_32x32x16_bf16(P##10, bh0, ACCB, 0, 0, 0); \
    ACCB = __builtin_amdgcn_mfma_f32_32x32x16_bf16(P##11, bh1, ACCB, 0, 0, 0); \
    ACCB = __builtin_amdgcn_mfma_f32_32x32x16_bf16(P##10, bl0, ACCB, 0, 0, 0); \
    ACCB = __builtin_amdgcn_mfma_f32_32x32x16_bf16(P##11, bl1, ACCB, 0, 0, 0); }

// ---------------- main: one wave = 64 rows, MFMA matvecs ---------------------
// C-frag (row,col): col = lane&31, row = 4*(lane>>5) + (j&3) + 8*(j>>2).
// Per-wave junction aliases: ushort[64][66] (bf16 acts) over uint[64][33]
// (raw f32 for the T2/T3 transposed folds). In-wave LDS is in-order; memcpy
// reads + asm memory fences order the ushort<->uint view switches.
__global__ __launch_bounds__(256) __attribute__((amdgpu_waves_per_eu(4, 4)))
void icnn_main(
    const float* __restrict__ eps,
    const float* __restrict__ W1,  const float* __restrict__ b1,
    const float* __restrict__ Wc0, const float* __restrict__ bc0,
    const float* __restrict__ Wc1, const float* __restrict__ bc1,
    const float* __restrict__ wout,
    float* __restrict__ out)
{
    __shared__ uint sbuf[4 * 2112];               // 33792 B
    const int tid  = threadIdx.x;
    const int lane = tid & 63, wib = tid >> 6;
    uint*   __restrict__ sw  = sbuf + wib * 2112;
    ushort* __restrict__ swh = (ushort*)sw;
    const int col = lane & 31, half = lane >> 5;
    const long rowg = (long)(blockIdx.x * 4 + wib) * 64 + lane;

    const float e11 = eps[rowg * 3 + 0];
    const float e22 = eps[rowg * 3 + 1];
    const float e12 = eps[rowg * 3 + 2];
    const float x1 = e11 + e22;
    const float x2 = e11 * e11 + 2.0f * e12 * e12 + e22 * e22;

    float g0 = wout[0], gq = wout[1];

    // ---- Stage A: z = sp(W1 z0 + b1) exactly per-row; bf16 -> junction
    #pragma unroll
    for (int u = 0; u < 32; u++) {
        float a = fmaf(W1[2 * u], x1, fmaf(W1[2 * u + 1], x2, b1[u]));
        swh[lane * 66 + u] = (ushort)bf16u(sp_only(a));
    }

    // ---- Stage B: u0 = Z A0^T (MFMA); d0 kept in frags; zn -> junction
    RDALLS(z)
    f32x16 acc0a = {}, acc0b = {};
    MATVEC(0, z, acc0a, acc0b)

    // c0 pre-activation via tiny MFMA (rank-2, bf16 x -> negligible err)
    const float x1s = __shfl(x1, col),      x2s = __shfl(x2, col);
    const float x1o = __shfl(x1, 32 + col), x2o = __shfl(x2, 32 + col);
    union { s8b v; uint d[4]; } xa0, xa1, wb;
    xa0.d[1] = xa0.d[2] = xa0.d[3] = 0;
    xa1.d[1] = xa1.d[2] = xa1.d[3] = 0;
    wb.d[1] = wb.d[2] = wb.d[3] = 0;
    xa0.d[0] = half ? 0u : (bf16u(x1s) | (bf16u(x2s) << 16));
    xa1.d[0] = half ? 0u : (bf16u(x1o) | (bf16u(x2o) << 16));
    wb.d[0]  = half ? 0u : (bf16u(Wc0[2 * col]) | (bf16u(Wc0[2 * col + 1]) << 16));
    f32x16 zz = {};
    f32x16 c0pa = __builtin_amdgcn_mfma_f32_32x32x16_bf16(xa0.v, wb.v, zz, 0, 0, 0);
    f32x16 c0pb = __builtin_amdgcn_mfma_f32_32x32x16_bf16(xa1.v, wb.v, zz, 0, 0, 0);

    const float bc0c = bc0[col];
    f32x16 d0a, d0b;
    #pragma unroll
    for (int j = 0; j < 16; j++) {
        const int rowl = 4 * half + (j & 3) + 8 * (j >> 2);
        float su; float t = sp_sig(acc0a[j], su);
        d0a[j] = kAct2 * t * su;
        swh[rowl * 66 + col] = (ushort)bf16u(fmaf(kActScale * t, t, sp_only(c0pa[j] + bc0c)));
        float su2; float t2 = sp_sig(acc0b[j], su2);
        d0b[j] = kAct2 * t2 * su2;
        swh[(rowl + 32) * 66 + col] = (ushort)bf16u(fmaf(kActScale * t2, t2, sp_only(c0pb[j] + bc0c)));
    }

    // ---- Stage C: u1 = ZN A1^T (issue first; T1 fold hides mfma latency)
    RDALLS(n)
    f32x16 acc1a = {}, acc1b = {};
    MATVEC(1, n, acc1a, acc1b)

    #pragma unroll
    for (int c = 0; c < 32; c++) {
        float c1 = fmaf(Wc1[2 * c], x1, fmaf(Wc1[2 * c + 1], x2, bc1[c]));
        float w = g_tab[4096 + c] * sig_only(c1);
        g0 = fmaf(Wc1[2 * c], w, g0);
        gq = fmaf(Wc1[2 * c + 1], w, gq);
    }

    const float aoutc = g_tab[4096 + col];
    #pragma unroll
    for (int j = 0; j < 16; j++) {
        const int rowl = 4 * half + (j & 3) + 8 * (j >> 2);
        float su; float t = sp_sig(acc1a[j], su);
        swh[rowl * 66 + col] = (ushort)bf16u(aoutc * kAct2 * t * su);
        float su2; float t2 = sp_sig(acc1b[j], su2);
        swh[(rowl + 32) * 66 + col] = (ushort)bf16u(aoutc * kAct2 * t2 * su2);
    }

    // ---- Stage D: g = D1 A1; gg = g*d0 -> junction (bf16); raw g -> T2 fold
    RDALLS(d)
    f32x16 acc2a = {}, acc2b = {};
    MATVEC(2, d, acc2a, acc2b)

    #pragma unroll
    for (int j = 0; j < 16; j++) {
        const int rowl = 4 * half + (j & 3) + 8 * (j >> 2);
        swh[rowl * 66 + col]        = (ushort)bf16u(acc2a[j] * d0a[j]);
        swh[(rowl + 32) * 66 + col] = (ushort)bf16u(acc2b[j] * d0b[j]);
    }
    RDALLS(g)                        // gg frags (read before raw overwrites)
    asm volatile("" ::: "memory");
    #pragma unroll
    for (int j = 0; j < 16; j++) {
        const int rowl = 4 * half + (j & 3) + 8 * (j >> 2);
        sw[rowl * 33 + col]        = __float_as_uint(acc2a[j]);
        sw[(rowl + 32) * 33 + col] = __float_as_uint(acc2b[j]);
    }
    // issue Stage E matvec now; T2 fold VALU hides its latency
    f32x16 acc3a = {}, acc3b = {};
    MATVEC(3, g, acc3a, acc3b)

    #pragma unroll
    for (int c = 0; c < 32; c++) {
        float v  = __uint_as_float(sw[lane * 33 + c]);
        float c0 = fmaf(Wc0[2 * c], x1, fmaf(Wc0[2 * c + 1], x2, bc0[c]));
        float t2v = v * sig_only(c0);
        g0 = fmaf(Wc0[2 * c], t2v, g0);
        gq = fmaf(Wc0[2 * c + 1], t2v, gq);
    }
    asm volatile("" ::: "memory");

    // ---- Stage E: raw acc3 -> transposed T3 fold with exact sig(a)
    #pragma unroll
    for (int j = 0; j < 16; j++) {
        const int rowl = 4 * half + (j & 3) + 8 * (j >> 2);
        sw[rowl * 33 + col]        = __float_as_uint(acc3a[j]);
        sw[(rowl + 32) * 33 + col] = __float_as_uint(acc3b[j]);
    }
    #pragma unroll
    for (int c = 0; c < 32; c++) {
        float v = __uint_as_float(sw[lane * 33 + c]);
        float a = fmaf(W1[2 * c], x1, fmaf(W1[2 * c + 1], x2, b1[c]));
        float t3 = v * sig_only(a);
        g0 = fmaf(W1[2 * c], t3, g0);
        gq = fmaf(W1[2 * c + 1], t3, gq);
    }

    const float cref = g_tab[4128];
    const float dI1 = g0 - cref;
    const float dI2 = gq;
    out[rowg * 3 + 0] = fmaf(2.0f * e11, dI2, dI1);
    out[rowg * 3 + 1] = fmaf(2.0f * e22, dI2, dI1);
    out[rowg * 3 + 2] = 2.0f * e12 * dI2;
}

extern "C" void kernel_launch(void* const* d_in, const int* in_sizes, int n_in,
                              void* d_out, int out_size, void* d_ws, size_t ws_size,
                              hipStream_t stream)
{
    (void)in_sizes; (void)n_in; (void)out_size; (void)d_ws; (void)ws_size;
    const float* eps    = (const float*)d_in[0];
    const float* W1     = (const float*)d_in[1];
    const float* b1     = (const float*)d_in[2];
    const float* rawA0  = (const float*)d_in[3];
    const float* rawA1  = (const float*)d_in[4];
    const float* Wc0    = (const float*)d_in[5];
    const float* bc0    = (const float*)d_in[6];
    const float* Wc1    = (const float*)d_in[7];
    const float* bc1    = (const float*)d_in[8];
    const float* rawAout= (const float*)d_in[9];
    const float* wout   = (const float*)d_in[10];
    float* out = (float*)d_out;

    icnn_prep<<<1, 256, 0, stream>>>(rawA0, rawA1, rawAout, W1, b1, Wc0, bc0, Wc1, bc1, wout);
    icnn_main<<<kBatch / 256, 256, 0, stream>>>(eps, W1, b1, Wc0, bc0, Wc1, bc1, wout, out);
}